// Round 1
// baseline (813.452 us; speedup 1.0000x reference)
//
#include <hip/hip_runtime.h>
#include <math.h>

// =====================================================================
// 3-layer GAT (PyG GATConv semantics) on MI355X.
// Strategy: on-device CSR build (by dst), then per-layer:
//   linear (fp32)  ->  per-node attention scores  ->  gather-style
//   online-softmax aggregation (one wave per (dst,head), no atomics).
// =====================================================================

#define NEG_SLOPE 0.2f

// ---------------- CSR build ----------------

__global__ __launch_bounds__(256) void edge_count(const int* __restrict__ ei, int E, int n,
                                                  int* __restrict__ deg) {
    int e = blockIdx.x * blockDim.x + threadIdx.x;
    int Etot = E + n;
    if (e >= Etot) return;
    int dst = (e < E) ? ei[E + e] : (e - E);   // self-loop for e >= E
    atomicAdd(&deg[dst], 1);
}

__global__ __launch_bounds__(1024) void scan_kernel(const int* __restrict__ deg,
                                                    int* __restrict__ offs,
                                                    int* __restrict__ cursor, int n) {
    __shared__ int sdata[1024];
    __shared__ int s_running;
    if (threadIdx.x == 0) s_running = 0;
    __syncthreads();
    const int CHUNK = 1024 * 8;
    for (int base = 0; base < n; base += CHUNK) {
        int vals[8];
        int sum = 0;
#pragma unroll
        for (int r = 0; r < 8; ++r) {
            int i = base + threadIdx.x * 8 + r;
            vals[r] = (i < n) ? deg[i] : 0;
            sum += vals[r];
        }
        sdata[threadIdx.x] = sum;
        __syncthreads();
        for (int off = 1; off < 1024; off <<= 1) {
            int v = (threadIdx.x >= off) ? sdata[threadIdx.x - off] : 0;
            __syncthreads();
            sdata[threadIdx.x] += v;
            __syncthreads();
        }
        int excl = sdata[threadIdx.x] - sum + s_running;
#pragma unroll
        for (int r = 0; r < 8; ++r) {
            int i = base + threadIdx.x * 8 + r;
            if (i < n) { offs[i] = excl; cursor[i] = excl; }
            excl += vals[r];
        }
        __syncthreads();
        if (threadIdx.x == 0) s_running += sdata[1023];
        __syncthreads();
    }
    if (threadIdx.x == 0) offs[n] = s_running;
}

__global__ __launch_bounds__(256) void edge_fill(const int* __restrict__ ei, int E, int n,
                                                 int* __restrict__ cursor,
                                                 int* __restrict__ csr) {
    int e = blockIdx.x * blockDim.x + threadIdx.x;
    int Etot = E + n;
    if (e >= Etot) return;
    int src, dst;
    if (e < E) { src = ei[e]; dst = ei[E + e]; }
    else       { src = e - E; dst = e - E; }
    int pos = atomicAdd(&cursor[dst], 1);
    csr[pos] = src;
}

// ---------------- Linear layers (fp32) ----------------

// Naive: thread = (node, col). Used for K=3 (layer1) and 256->32 (layer3).
template <int K, int COLS>
__global__ __launch_bounds__(256) void linear_naive(const float* __restrict__ x,
                                                    const float* __restrict__ W,
                                                    float* __restrict__ out, int n) {
    constexpr int NPB = 256 / COLS;
    int c = threadIdx.x % COLS;
    int node = blockIdx.x * NPB + threadIdx.x / COLS;
    if (node >= n) return;
    const float* xr = x + (size_t)node * K;
    float a0 = 0.f, a1 = 0.f, a2 = 0.f, a3 = 0.f;
    int k = 0;
    for (; k + 3 < K; k += 4) {
        a0 = fmaf(xr[k + 0], W[(k + 0) * COLS + c], a0);
        a1 = fmaf(xr[k + 1], W[(k + 1) * COLS + c], a1);
        a2 = fmaf(xr[k + 2], W[(k + 2) * COLS + c], a2);
        a3 = fmaf(xr[k + 3], W[(k + 3) * COLS + c], a3);
    }
    for (; k < K; ++k) a0 = fmaf(xr[k], W[k * COLS + c], a0);
    out[(size_t)node * COLS + c] = (a0 + a1) + (a2 + a3);
}

// Tiled 256x256 GEMM for layer 2: block = 32 nodes x 128 cols, thread = 4x4.
__global__ __launch_bounds__(256) void linear256(const float* __restrict__ x,
                                                 const float* __restrict__ W,
                                                 float* __restrict__ out, int n) {
    __shared__ float xs[64][33];          // K-chunk 64 x 32 nodes (+1 pad)
    int n0 = blockIdx.x * 32;
    int c0 = blockIdx.y * 128;
    int ci = threadIdx.x & 31;            // col group: cols c0 + ci*4 .. +3
    int ni = threadIdx.x >> 5;            // node group: nodes n0 + ni*4 .. +3
    float acc[4][4] = {};
    for (int kb = 0; kb < 256; kb += 64) {
        __syncthreads();
#pragma unroll
        for (int r = 0; r < 8; ++r) {
            int idx = r * 256 + threadIdx.x;   // 0..2047
            int nn = idx >> 6;
            int kk = idx & 63;
            int node = n0 + nn;
            xs[kk][nn] = (node < n) ? x[(size_t)node * 256 + kb + kk] : 0.f;
        }
        __syncthreads();
        for (int k = 0; k < 64; ++k) {
            float4 wv = *(const float4*)&W[(size_t)(kb + k) * 256 + c0 + ci * 4];
            float xv[4];
#pragma unroll
            for (int i = 0; i < 4; ++i) xv[i] = xs[k][ni * 4 + i];
#pragma unroll
            for (int i = 0; i < 4; ++i) {
                acc[i][0] = fmaf(xv[i], wv.x, acc[i][0]);
                acc[i][1] = fmaf(xv[i], wv.y, acc[i][1]);
                acc[i][2] = fmaf(xv[i], wv.z, acc[i][2]);
                acc[i][3] = fmaf(xv[i], wv.w, acc[i][3]);
            }
        }
    }
#pragma unroll
    for (int i = 0; i < 4; ++i) {
        int node = n0 + ni * 4 + i;
        if (node < n)
            *(float4*)&out[(size_t)node * 256 + c0 + ci * 4] =
                make_float4(acc[i][0], acc[i][1], acc[i][2], acc[i][3]);
    }
}

// ---------------- Attention scores: s_src/s_dst = sum_c h*a ----------------

template <int HEADS, int C>
__global__ __launch_bounds__(256) void compute_scores(const float* __restrict__ h,
                                                      const float* __restrict__ asrc,
                                                      const float* __restrict__ adst,
                                                      float* __restrict__ ssrc,
                                                      float* __restrict__ sdst, int n) {
    int w = blockIdx.x * (blockDim.x >> 6) + (threadIdx.x >> 6);
    int lane = threadIdx.x & 63;
    if (w >= n * HEADS) return;
    int node = w / HEADS;
    int head = w % HEADS;
    float va = 0.f, vb = 0.f;
    if (lane < C) {
        float v = h[(size_t)node * (HEADS * C) + head * C + lane];
        va = v * asrc[head * C + lane];
        vb = v * adst[head * C + lane];
    }
#pragma unroll
    for (int o = 32; o > 0; o >>= 1) {
        va += __shfl_xor(va, o);
        vb += __shfl_xor(vb, o);
    }
    if (lane == 0) { ssrc[w] = va; sdst[w] = vb; }
}

// ---------------- Gather aggregation, online softmax ----------------
// One wave per (dst node, head). Lanes = channels. Edge chunks of 64.

template <int HEADS, int C, bool RELU>
__global__ __launch_bounds__(256) void gat_aggregate(const float* __restrict__ h,
                                                     const float* __restrict__ ssrc,
                                                     const float* __restrict__ sdst,
                                                     const int* __restrict__ offs,
                                                     const int* __restrict__ csr,
                                                     const float* __restrict__ bias,
                                                     float* __restrict__ out, int n) {
    int w = blockIdx.x * (blockDim.x >> 6) + (threadIdx.x >> 6);
    int lane = threadIdx.x & 63;
    if (w >= n * HEADS) return;
    int node = w / HEADS;
    int head = w % HEADS;
    int beg = offs[node];
    int end = offs[node + 1];
    float sd = sdst[(size_t)node * HEADS + head];
    float m = -INFINITY, l = 0.f, acc = 0.f;

    for (int base = beg; base < end; base += 64) {
        int j = base + lane;
        bool valid = (j < end);
        int sj = 0;
        float logit = -INFINITY;
        if (valid) {
            sj = csr[j];
            float xv = ssrc[(size_t)sj * HEADS + head] + sd;
            logit = (xv > 0.f) ? xv : NEG_SLOPE * xv;
        }
        // chunk max
        float cm = logit;
#pragma unroll
        for (int o = 32; o > 0; o >>= 1) cm = fmaxf(cm, __shfl_xor(cm, o));
        float nm = fmaxf(m, cm);
        float scale = __expf(m - nm);    // m = -inf -> 0
        l *= scale;
        acc *= scale;
        float ex = valid ? __expf(logit - nm) : 0.f;
        float es = ex;
#pragma unroll
        for (int o = 32; o > 0; o >>= 1) es += __shfl_xor(es, o);
        l += es;
        m = nm;
        int cnt = min(64, end - base);
        for (int t = 0; t < cnt; ++t) {
            float a = __shfl(ex, t);
            int s = __shfl(sj, t);
            if (lane < C)
                acc = fmaf(a, h[(size_t)s * (HEADS * C) + head * C + lane], acc);
        }
    }
    if (lane < C) {
        float o = acc / l + bias[head * C + lane];
        if (RELU) o = fmaxf(o, 0.f);
        out[(size_t)node * (HEADS * C) + head * C + lane] = o;
    }
}

// ---------------- Launch ----------------

extern "C" void kernel_launch(void* const* d_in, const int* in_sizes, int n_in,
                              void* d_out, int out_size, void* d_ws, size_t ws_size,
                              hipStream_t stream) {
    const float* x   = (const float*)d_in[0];
    const int*   ei  = (const int*)d_in[1];
    const float* W1  = (const float*)d_in[2];
    const float* as1 = (const float*)d_in[3];
    const float* ad1 = (const float*)d_in[4];
    const float* b1  = (const float*)d_in[5];
    const float* W2  = (const float*)d_in[6];
    const float* as2 = (const float*)d_in[7];
    const float* ad2 = (const float*)d_in[8];
    const float* b2  = (const float*)d_in[9];
    const float* W3  = (const float*)d_in[10];
    const float* as3 = (const float*)d_in[11];
    const float* ad3 = (const float*)d_in[12];
    const float* b3  = (const float*)d_in[13];
    float* out = (float*)d_out;

    const int n = in_sizes[0] / 3;     // 50000
    const int E = in_sizes[1] / 2;     // 400000
    const int Etot = E + n;            // with self-loops

    // workspace layout
    char* ws = (char*)d_ws;
    float* bufA = (float*)ws;  ws += (size_t)n * 256 * sizeof(float);   // 51.2 MB
    float* bufB = (float*)ws;  ws += (size_t)n * 256 * sizeof(float);   // 51.2 MB
    float* ssrc = (float*)ws;  ws += (size_t)n * 4 * sizeof(float);
    float* sdst = (float*)ws;  ws += (size_t)n * 4 * sizeof(float);
    int* deg    = (int*)ws;    ws += (size_t)n * sizeof(int);
    int* offs   = (int*)ws;    ws += (size_t)(n + 1) * sizeof(int) + 12; // keep alignment
    int* cursor = (int*)ws;    ws += (size_t)n * sizeof(int);
    int* csr    = (int*)ws;    ws += (size_t)Etot * sizeof(int);

    // ---- CSR build (by dst) ----
    hipMemsetAsync(deg, 0, (size_t)n * sizeof(int), stream);
    int eblocks = (Etot + 255) / 256;
    edge_count<<<eblocks, 256, 0, stream>>>(ei, E, n, deg);
    scan_kernel<<<1, 1024, 0, stream>>>(deg, offs, cursor, n);
    edge_fill<<<eblocks, 256, 0, stream>>>(ei, E, n, cursor, csr);

    // ---- Layer 1: 3 -> (4 heads x 64), concat, relu ----
    linear_naive<3, 256><<<n, 256, 0, stream>>>(x, W1, bufA, n);
    compute_scores<4, 64><<<n, 256, 0, stream>>>(bufA, as1, ad1, ssrc, sdst, n);
    gat_aggregate<4, 64, true><<<n, 256, 0, stream>>>(bufA, ssrc, sdst, offs, csr, b1, bufB, n);

    // ---- Layer 2: 256 -> (4 x 64), concat, relu ----
    dim3 g2((n + 31) / 32, 2);
    linear256<<<g2, 256, 0, stream>>>(bufB, W2, bufA, n);
    compute_scores<4, 64><<<n, 256, 0, stream>>>(bufA, as2, ad2, ssrc, sdst, n);
    gat_aggregate<4, 64, true><<<n, 256, 0, stream>>>(bufA, ssrc, sdst, offs, csr, b2, bufB, n);

    // ---- Layer 3: 256 -> (1 x 32), mean(=identity), no relu ----
    linear_naive<256, 32><<<(n + 7) / 8, 256, 0, stream>>>(bufB, W3, bufA, n);
    compute_scores<1, 32><<<(n * 1 + 3) / 4, 256, 0, stream>>>(bufA, as3, ad3, ssrc, sdst, n);
    gat_aggregate<1, 32, false><<<(n * 1 + 3) / 4, 256, 0, stream>>>(bufA, ssrc, sdst, offs, csr, b3, out, n);
}

// Round 2
// 663.127 us; speedup vs baseline: 1.2267x; 1.2267x over previous
//
#include <hip/hip_runtime.h>
#include <math.h>

// =====================================================================
// 3-layer GAT (PyG GATConv semantics) on MI355X.
// CSR-by-dst build, then per layer: linear -> scores -> gather-style
// online-softmax aggregation (merged 4-head wave for layers 1/2).
// =====================================================================

#define NEG_SLOPE 0.2f

// ---------------- CSR build ----------------

__global__ __launch_bounds__(256) void edge_count(const int* __restrict__ ei, int E, int n,
                                                  int* __restrict__ deg) {
    int e = blockIdx.x * blockDim.x + threadIdx.x;
    int Etot = E + n;
    if (e >= Etot) return;
    int dst = (e < E) ? ei[E + e] : (e - E);   // self-loop for e >= E
    atomicAdd(&deg[dst], 1);
}

__global__ __launch_bounds__(1024) void scan_kernel(const int* __restrict__ deg,
                                                    int* __restrict__ offs,
                                                    int* __restrict__ cursor, int n) {
    __shared__ int sdata[1024];
    __shared__ int s_running;
    if (threadIdx.x == 0) s_running = 0;
    __syncthreads();
    const int CHUNK = 1024 * 8;
    for (int base = 0; base < n; base += CHUNK) {
        int vals[8];
        int sum = 0;
#pragma unroll
        for (int r = 0; r < 8; ++r) {
            int i = base + threadIdx.x * 8 + r;
            vals[r] = (i < n) ? deg[i] : 0;
            sum += vals[r];
        }
        sdata[threadIdx.x] = sum;
        __syncthreads();
        for (int off = 1; off < 1024; off <<= 1) {
            int v = (threadIdx.x >= off) ? sdata[threadIdx.x - off] : 0;
            __syncthreads();
            sdata[threadIdx.x] += v;
            __syncthreads();
        }
        int excl = sdata[threadIdx.x] - sum + s_running;
#pragma unroll
        for (int r = 0; r < 8; ++r) {
            int i = base + threadIdx.x * 8 + r;
            if (i < n) { offs[i] = excl; cursor[i] = excl; }
            excl += vals[r];
        }
        __syncthreads();
        if (threadIdx.x == 0) s_running += sdata[1023];
        __syncthreads();
    }
    if (threadIdx.x == 0) offs[n] = s_running;
}

__global__ __launch_bounds__(256) void edge_fill(const int* __restrict__ ei, int E, int n,
                                                 int* __restrict__ cursor,
                                                 int* __restrict__ csr) {
    int e = blockIdx.x * blockDim.x + threadIdx.x;
    int Etot = E + n;
    if (e >= Etot) return;
    int src, dst;
    if (e < E) { src = ei[e]; dst = ei[E + e]; }
    else       { src = e - E; dst = e - E; }
    int pos = atomicAdd(&cursor[dst], 1);
    csr[pos] = src;
}

// ---------------- Linear layers (fp32) ----------------

// Naive: thread = (node, col). Used for K=3 (layer1) and 256->32 (layer3).
template <int K, int COLS>
__global__ __launch_bounds__(256) void linear_naive(const float* __restrict__ x,
                                                    const float* __restrict__ W,
                                                    float* __restrict__ out, int n) {
    constexpr int NPB = 256 / COLS;
    int c = threadIdx.x % COLS;
    int node = blockIdx.x * NPB + threadIdx.x / COLS;
    if (node >= n) return;
    const float* xr = x + (size_t)node * K;
    float a0 = 0.f, a1 = 0.f, a2 = 0.f, a3 = 0.f;
    int k = 0;
    for (; k + 3 < K; k += 4) {
        a0 = fmaf(xr[k + 0], W[(k + 0) * COLS + c], a0);
        a1 = fmaf(xr[k + 1], W[(k + 1) * COLS + c], a1);
        a2 = fmaf(xr[k + 2], W[(k + 2) * COLS + c], a2);
        a3 = fmaf(xr[k + 3], W[(k + 3) * COLS + c], a3);
    }
    for (; k < K; ++k) a0 = fmaf(xr[k], W[k * COLS + c], a0);
    out[(size_t)node * COLS + c] = (a0 + a1) + (a2 + a3);
}

// Tiled 256x256 GEMM for layer 2: block = 64 nodes x 128 cols, thread = 8x4.
__global__ __launch_bounds__(256) void linear256(const float* __restrict__ x,
                                                 const float* __restrict__ W,
                                                 float* __restrict__ out, int n) {
    __shared__ float xs[32][68];          // K-chunk 32 x 64 nodes (+4 pad, 16B-aligned rows)
    int n0 = blockIdx.x * 64;
    int c0 = blockIdx.y * 128;
    int ci = threadIdx.x & 31;            // col group: cols c0 + ci*4 .. +3
    int ni = threadIdx.x >> 5;            // node group: nodes n0 + ni*8 .. +7
    float acc[8][4] = {};
    for (int kb = 0; kb < 256; kb += 32) {
        __syncthreads();
#pragma unroll
        for (int r = 0; r < 8; ++r) {
            int idx = r * 256 + threadIdx.x;   // 0..2047 = 64 nodes x 32 k
            int nn = idx >> 5;
            int kk = idx & 31;
            int node = n0 + nn;
            xs[kk][nn] = (node < n) ? x[(size_t)node * 256 + kb + kk] : 0.f;
        }
        __syncthreads();
#pragma unroll
        for (int k = 0; k < 32; ++k) {
            float4 wv = *(const float4*)&W[(size_t)(kb + k) * 256 + c0 + ci * 4];
            float4 xa = *(const float4*)&xs[k][ni * 8];
            float4 xb = *(const float4*)&xs[k][ni * 8 + 4];
            float xv[8] = {xa.x, xa.y, xa.z, xa.w, xb.x, xb.y, xb.z, xb.w};
#pragma unroll
            for (int i = 0; i < 8; ++i) {
                acc[i][0] = fmaf(xv[i], wv.x, acc[i][0]);
                acc[i][1] = fmaf(xv[i], wv.y, acc[i][1]);
                acc[i][2] = fmaf(xv[i], wv.z, acc[i][2]);
                acc[i][3] = fmaf(xv[i], wv.w, acc[i][3]);
            }
        }
    }
#pragma unroll
    for (int i = 0; i < 8; ++i) {
        int node = n0 + ni * 8 + i;
        if (node < n)
            *(float4*)&out[(size_t)node * 256 + c0 + ci * 4] =
                make_float4(acc[i][0], acc[i][1], acc[i][2], acc[i][3]);
    }
}

// ---------------- Attention scores: s_src/s_dst = sum_c h*a ----------------

template <int HEADS, int C>
__global__ __launch_bounds__(256) void compute_scores(const float* __restrict__ h,
                                                      const float* __restrict__ asrc,
                                                      const float* __restrict__ adst,
                                                      float* __restrict__ ssrc,
                                                      float* __restrict__ sdst, int n) {
    int w = blockIdx.x * (blockDim.x >> 6) + (threadIdx.x >> 6);
    int lane = threadIdx.x & 63;
    if (w >= n * HEADS) return;
    int node = w / HEADS;
    int head = w % HEADS;
    float va = 0.f, vb = 0.f;
    if (lane < C) {
        float v = h[(size_t)node * (HEADS * C) + head * C + lane];
        va = v * asrc[head * C + lane];
        vb = v * adst[head * C + lane];
    }
#pragma unroll
    for (int o = 32; o > 0; o >>= 1) {
        va += __shfl_xor(va, o);
        vb += __shfl_xor(vb, o);
    }
    if (lane == 0) { ssrc[w] = va; sdst[w] = vb; }
}

// ---------------- Merged 4-head aggregation (layers 1 & 2) ----------------
// One wave per dst node. Lane l: float4 acc covering channels l*4..l*4+3
// (head hA = l>>4); softmax state for head hB = l&3, edge slot eL = l>>2
// (16 edges/chunk x 4 heads). No atomics.

__global__ __launch_bounds__(256) void gat_aggregate_m4(const float* __restrict__ h,
                                                        const float* __restrict__ ssrc,
                                                        const float* __restrict__ sdst,
                                                        const int* __restrict__ offs,
                                                        const int* __restrict__ csr,
                                                        const float* __restrict__ bias,
                                                        float* __restrict__ out, int n) {
    int node = blockIdx.x * 4 + (threadIdx.x >> 6);
    int lane = threadIdx.x & 63;
    if (node >= n) return;
    const int hB = lane & 3;
    const int eL = lane >> 2;
    const int hA = lane >> 4;
    int beg = offs[node], end = offs[node + 1];
    float sd = sdst[node * 4 + hB];
    float m = -INFINITY, l = 0.f;
    float4 acc = make_float4(0.f, 0.f, 0.f, 0.f);

    for (int base = beg; base < end; base += 16) {
        int j = base + eL;
        bool valid = (j < end);
        int sj = valid ? csr[j] : 0;
        float logit = -INFINITY;
        if (valid) {
            float xv = ssrc[sj * 4 + hB] + sd;
            logit = (xv > 0.f) ? xv : NEG_SLOPE * xv;
        }
        // per-head chunk max (reduce over edge slots; xor 4..32 keeps l&3)
        float cm = logit;
        cm = fmaxf(cm, __shfl_xor(cm, 4));
        cm = fmaxf(cm, __shfl_xor(cm, 8));
        cm = fmaxf(cm, __shfl_xor(cm, 16));
        cm = fmaxf(cm, __shfl_xor(cm, 32));
        float nm = fmaxf(m, cm);
        float scale = __expf(m - nm);       // m=-inf -> 0
        float ex = valid ? __expf(logit - nm) : 0.f;
        float es = ex;
        es += __shfl_xor(es, 4);
        es += __shfl_xor(es, 8);
        es += __shfl_xor(es, 16);
        es += __shfl_xor(es, 32);
        l = l * scale + es;
        m = nm;
        float sA = __shfl(scale, hA);       // scale for accumulation head
        acc.x *= sA; acc.y *= sA; acc.z *= sA; acc.w *= sA;

        int cnt = min(16, end - base);
        for (int t = 0; t < cnt; t += 4) {   // t <= 12, so tt*4+hA <= 63
#pragma unroll
            for (int u = 0; u < 4; ++u) {
                int tt = t + u;
                float a = __shfl(ex, tt * 4 + hA);   // 0 for invalid edges
                int s = __shfl(sj, tt * 4);          // 0 for invalid (safe addr)
                const float4 hv = *(const float4*)&h[(size_t)s * 256 + lane * 4];
                acc.x = fmaf(a, hv.x, acc.x);
                acc.y = fmaf(a, hv.y, acc.y);
                acc.z = fmaf(a, hv.z, acc.z);
                acc.w = fmaf(a, hv.w, acc.w);
            }
        }
    }
    float lf = __shfl(l, hA);
    float inv = 1.f / lf;
    const float4 bv = *(const float4*)&bias[lane * 4];
    float4 o;
    o.x = fmaxf(fmaf(acc.x, inv, bv.x), 0.f);   // relu (layers 1 & 2 only)
    o.y = fmaxf(fmaf(acc.y, inv, bv.y), 0.f);
    o.z = fmaxf(fmaf(acc.z, inv, bv.z), 0.f);
    o.w = fmaxf(fmaf(acc.w, inv, bv.w), 0.f);
    *(float4*)&out[(size_t)node * 256 + lane * 4] = o;
}

// ---------------- Single-head aggregation (layer 3, C=32, no relu) --------

__global__ __launch_bounds__(256) void gat_aggregate_h1(const float* __restrict__ h,
                                                        const float* __restrict__ ssrc,
                                                        const float* __restrict__ sdst,
                                                        const int* __restrict__ offs,
                                                        const int* __restrict__ csr,
                                                        const float* __restrict__ bias,
                                                        float* __restrict__ out, int n) {
    int node = blockIdx.x * 4 + (threadIdx.x >> 6);
    int lane = threadIdx.x & 63;
    if (node >= n) return;
    int beg = offs[node], end = offs[node + 1];
    float sd = sdst[node];
    float m = -INFINITY, l = 0.f, acc = 0.f;

    for (int base = beg; base < end; base += 64) {
        int j = base + lane;
        bool valid = (j < end);
        int sj = valid ? csr[j] : 0;
        float logit = -INFINITY;
        if (valid) {
            float xv = ssrc[sj] + sd;
            logit = (xv > 0.f) ? xv : NEG_SLOPE * xv;
        }
        float cm = logit;
#pragma unroll
        for (int o = 32; o > 0; o >>= 1) cm = fmaxf(cm, __shfl_xor(cm, o));
        float nm = fmaxf(m, cm);
        float scale = __expf(m - nm);
        float ex = valid ? __expf(logit - nm) : 0.f;
        float es = ex;
#pragma unroll
        for (int o = 32; o > 0; o >>= 1) es += __shfl_xor(es, o);
        l = l * scale + es;
        m = nm;
        acc *= scale;
        int cnt = min(64, end - base);
        for (int t = 0; t < cnt; t += 4) {
#pragma unroll
            for (int u = 0; u < 4; ++u) {
                float a = __shfl(ex, t + u);
                int s = __shfl(sj, t + u);
                if (lane < 32) acc = fmaf(a, h[(size_t)s * 32 + lane], acc);
            }
        }
    }
    if (lane < 32) out[(size_t)node * 32 + lane] = acc / l + bias[lane];
}

// ---------------- Launch ----------------

extern "C" void kernel_launch(void* const* d_in, const int* in_sizes, int n_in,
                              void* d_out, int out_size, void* d_ws, size_t ws_size,
                              hipStream_t stream) {
    const float* x   = (const float*)d_in[0];
    const int*   ei  = (const int*)d_in[1];
    const float* W1  = (const float*)d_in[2];
    const float* as1 = (const float*)d_in[3];
    const float* ad1 = (const float*)d_in[4];
    const float* b1  = (const float*)d_in[5];
    const float* W2  = (const float*)d_in[6];
    const float* as2 = (const float*)d_in[7];
    const float* ad2 = (const float*)d_in[8];
    const float* b2  = (const float*)d_in[9];
    const float* W3  = (const float*)d_in[10];
    const float* as3 = (const float*)d_in[11];
    const float* ad3 = (const float*)d_in[12];
    const float* b3  = (const float*)d_in[13];
    float* out = (float*)d_out;

    const int n = in_sizes[0] / 3;     // 50000
    const int E = in_sizes[1] / 2;     // 400000
    const int Etot = E + n;            // with self-loops

    // workspace layout
    char* ws = (char*)d_ws;
    float* bufA = (float*)ws;  ws += (size_t)n * 256 * sizeof(float);   // 51.2 MB
    float* bufB = (float*)ws;  ws += (size_t)n * 256 * sizeof(float);   // 51.2 MB
    float* ssrc = (float*)ws;  ws += (size_t)n * 4 * sizeof(float);
    float* sdst = (float*)ws;  ws += (size_t)n * 4 * sizeof(float);
    int* deg    = (int*)ws;    ws += (size_t)n * sizeof(int);
    int* offs   = (int*)ws;    ws += (size_t)(n + 1) * sizeof(int) + 12; // keep alignment
    int* cursor = (int*)ws;    ws += (size_t)n * sizeof(int);
    int* csr    = (int*)ws;    ws += (size_t)Etot * sizeof(int);

    // ---- CSR build (by dst) ----
    hipMemsetAsync(deg, 0, (size_t)n * sizeof(int), stream);
    int eblocks = (Etot + 255) / 256;
    edge_count<<<eblocks, 256, 0, stream>>>(ei, E, n, deg);
    scan_kernel<<<1, 1024, 0, stream>>>(deg, offs, cursor, n);
    edge_fill<<<eblocks, 256, 0, stream>>>(ei, E, n, cursor, csr);

    int nb4 = (n + 3) / 4;

    // ---- Layer 1: 3 -> (4 heads x 64), concat, relu ----
    linear_naive<3, 256><<<n, 256, 0, stream>>>(x, W1, bufA, n);
    compute_scores<4, 64><<<n, 256, 0, stream>>>(bufA, as1, ad1, ssrc, sdst, n);
    gat_aggregate_m4<<<nb4, 256, 0, stream>>>(bufA, ssrc, sdst, offs, csr, b1, bufB, n);

    // ---- Layer 2: 256 -> (4 x 64), concat, relu ----
    dim3 g2((n + 63) / 64, 2);
    linear256<<<g2, 256, 0, stream>>>(bufB, W2, bufA, n);
    compute_scores<4, 64><<<n, 256, 0, stream>>>(bufA, as2, ad2, ssrc, sdst, n);
    gat_aggregate_m4<<<nb4, 256, 0, stream>>>(bufA, ssrc, sdst, offs, csr, b2, bufB, n);

    // ---- Layer 3: 256 -> (1 x 32), mean(=identity), no relu ----
    linear_naive<256, 32><<<(n + 7) / 8, 256, 0, stream>>>(bufB, W3, bufA, n);
    compute_scores<1, 32><<<nb4, 256, 0, stream>>>(bufA, as3, ad3, ssrc, sdst, n);
    gat_aggregate_h1<<<nb4, 256, 0, stream>>>(bufA, ssrc, sdst, offs, csr, b3, out, n);
}

// Round 4
// 628.229 us; speedup vs baseline: 1.2948x; 1.0556x over previous
//
#include <hip/hip_runtime.h>
#include <math.h>

// =====================================================================
// 3-layer GAT (PyG GATConv) on MI355X.
// fp32 data plane (proven accurate/robust) + split-precision bf16 MFMA
// GEMMs (hi/lo decomposition, fp32-equivalent accuracy, deterministic).
// CSR-by-dst gather aggregation with merged-head online softmax.
// =====================================================================

#define NEG_SLOPE 0.2f

typedef unsigned short u16;
typedef short bf16x8 __attribute__((ext_vector_type(8)));
typedef float floatx4 __attribute__((ext_vector_type(4)));

__device__ __forceinline__ float b2f(u16 u) {
    return __uint_as_float(((unsigned int)u) << 16);
}
__device__ __forceinline__ u16 f2b(float f) {
    unsigned int u = __float_as_uint(f);
    unsigned int r = (u + 0x7fffu + ((u >> 16) & 1u)) >> 16;   // RNE
    return (u16)r;
}

// ---------------- CSR build ----------------

__global__ __launch_bounds__(256) void edge_count(const int* __restrict__ ei, int E, int n,
                                                  int* __restrict__ deg) {
    int e = blockIdx.x * blockDim.x + threadIdx.x;
    int Etot = E + n;
    if (e >= Etot) return;
    int dst = (e < E) ? ei[E + e] : (e - E);   // self-loop for e >= E
    atomicAdd(&deg[dst], 1);
}

__global__ __launch_bounds__(1024) void scan_kernel(const int* __restrict__ deg,
                                                    int* __restrict__ offs,
                                                    int* __restrict__ cursor, int n) {
    __shared__ int sdata[1024];
    __shared__ int s_running;
    if (threadIdx.x == 0) s_running = 0;
    __syncthreads();
    const int CHUNK = 1024 * 8;
    for (int base = 0; base < n; base += CHUNK) {
        int vals[8];
        int sum = 0;
#pragma unroll
        for (int r = 0; r < 8; ++r) {
            int i = base + threadIdx.x * 8 + r;
            vals[r] = (i < n) ? deg[i] : 0;
            sum += vals[r];
        }
        sdata[threadIdx.x] = sum;
        __syncthreads();
        for (int off = 1; off < 1024; off <<= 1) {
            int v = (threadIdx.x >= off) ? sdata[threadIdx.x - off] : 0;
            __syncthreads();
            sdata[threadIdx.x] += v;
            __syncthreads();
        }
        int excl = sdata[threadIdx.x] - sum + s_running;
#pragma unroll
        for (int r = 0; r < 8; ++r) {
            int i = base + threadIdx.x * 8 + r;
            if (i < n) { offs[i] = excl; cursor[i] = excl; }
            excl += vals[r];
        }
        __syncthreads();
        if (threadIdx.x == 0) s_running += sdata[1023];
        __syncthreads();
    }
    if (threadIdx.x == 0) offs[n] = s_running;
}

__global__ __launch_bounds__(256) void edge_fill(const int* __restrict__ ei, int E, int n,
                                                 int* __restrict__ cursor,
                                                 int* __restrict__ csr) {
    int e = blockIdx.x * blockDim.x + threadIdx.x;
    int Etot = E + n;
    if (e >= Etot) return;
    int src, dst;
    if (e < E) { src = ei[e]; dst = ei[E + e]; }
    else       { src = e - E; dst = e - E; }
    int pos = atomicAdd(&cursor[dst], 1);
    csr[pos] = src;
}

// -------- Weight transpose + hi/lo bf16 split: Wt[n][k] = W[k][n] --------

__global__ __launch_bounds__(256) void transpose_split(const float* __restrict__ W,
                                                       u16* __restrict__ Whi,
                                                       u16* __restrict__ Wlo, int K, int N) {
    int idx = blockIdx.x * blockDim.x + threadIdx.x;
    if (idx >= K * N) return;
    int k = idx / N, c = idx % N;
    float w = W[idx];
    u16 hi = f2b(w);
    u16 lo = f2b(w - b2f(hi));
    Whi[(size_t)c * K + k] = hi;
    Wlo[(size_t)c * K + k] = lo;
}

// ---------------- Layer-1 linear (K=3), fp32 out ----------------

__global__ __launch_bounds__(256) void linear1(const float* __restrict__ x,
                                               const float* __restrict__ W,
                                               float* __restrict__ out, int n) {
    int node = blockIdx.x;
    if (node >= n) return;
    int c = threadIdx.x;
    float x0 = x[node * 3 + 0], x1 = x[node * 3 + 1], x2 = x[node * 3 + 2];
    out[(size_t)node * 256 + c] = fmaf(x0, W[c], fmaf(x1, W[256 + c], x2 * W[512 + c]));
}

// ------- Split-precision MFMA GEMM: out[n x NCOLS] = A[n x 256] * W^T ----
// A fp32 row-major, split to hi/lo bf16 in-register. W pre-split/transposed
// bf16 [NCOLS][256]. D = Ahi*Whi + Alo*Whi + Ahi*Wlo (fp32 acc), rel err
// ~1e-5. Fragment layouts (verified): A[m=lane&15][k=(lane>>4)*8+j];
// D reg r of lane l -> row (l>>4)*4+r, col l&15.

template <int NCOLS>
__global__ __launch_bounds__(256) void gemm_mfma_split(const float* __restrict__ A,
                                                       const u16* __restrict__ Whi,
                                                       const u16* __restrict__ Wlo,
                                                       float* __restrict__ outf, int n) {
    constexpr int CT = (NCOLS >= 64) ? 4 : (NCOLS / 16);
    int w = threadIdx.x >> 6;
    int l = threadIdx.x & 63;
    int m0 = blockIdx.x * 64 + w * 16;
    int c0 = blockIdx.y * 64;
    int lm = l & 15, q = l >> 4;
    floatx4 acc[CT] = {};
    const float* arow = A + (size_t)(m0 + lm) * 256 + q * 8;
#pragma unroll
    for (int kb = 0; kb < 256; kb += 32) {
        float4 a0 = *(const float4*)(arow + kb);
        float4 a1 = *(const float4*)(arow + kb + 4);
        float av[8] = {a0.x, a0.y, a0.z, a0.w, a1.x, a1.y, a1.z, a1.w};
        bf16x8 ahi, alo;
#pragma unroll
        for (int j = 0; j < 8; ++j) {
            u16 hi = f2b(av[j]);
            ahi[j] = (short)hi;
            alo[j] = (short)f2b(av[j] - b2f(hi));
        }
#pragma unroll
        for (int ct = 0; ct < CT; ++ct) {
            size_t boff = (size_t)(c0 + ct * 16 + lm) * 256 + kb + q * 8;
            bf16x8 bhi = *(const bf16x8*)(Whi + boff);
            bf16x8 blo = *(const bf16x8*)(Wlo + boff);
            acc[ct] = __builtin_amdgcn_mfma_f32_16x16x32_bf16(ahi, bhi, acc[ct], 0, 0, 0);
            acc[ct] = __builtin_amdgcn_mfma_f32_16x16x32_bf16(alo, bhi, acc[ct], 0, 0, 0);
            acc[ct] = __builtin_amdgcn_mfma_f32_16x16x32_bf16(ahi, blo, acc[ct], 0, 0, 0);
        }
    }
#pragma unroll
    for (int ct = 0; ct < CT; ++ct) {
#pragma unroll
        for (int r = 0; r < 4; ++r) {
            int row = m0 + q * 4 + r;
            if (row < n)
                outf[(size_t)row * NCOLS + c0 + ct * 16 + lm] = acc[ct][r];
        }
    }
}

// ---------------- Attention scores: s_src/s_dst = sum_c h*a ----------------

template <int HEADS, int C>
__global__ __launch_bounds__(256) void compute_scores(const float* __restrict__ h,
                                                      const float* __restrict__ asrc,
                                                      const float* __restrict__ adst,
                                                      float* __restrict__ ssrc,
                                                      float* __restrict__ sdst, int n) {
    int w = blockIdx.x * (blockDim.x >> 6) + (threadIdx.x >> 6);
    int lane = threadIdx.x & 63;
    if (w >= n * HEADS) return;
    int node = w / HEADS;
    int head = w % HEADS;
    float va = 0.f, vb = 0.f;
    if (lane < C) {
        float v = h[(size_t)node * (HEADS * C) + head * C + lane];
        va = v * asrc[head * C + lane];
        vb = v * adst[head * C + lane];
    }
#pragma unroll
    for (int o = 32; o > 0; o >>= 1) {
        va += __shfl_xor(va, o);
        vb += __shfl_xor(vb, o);
    }
    if (lane == 0) { ssrc[w] = va; sdst[w] = vb; }
}

// ---------------- Merged 4-head aggregation (layers 1 & 2) ----------------
// One wave per dst node. Lane l: float4 acc covering channels l*4..l*4+3
// (head hA = l>>4); softmax state for head hB = l&3, edge slot eL = l>>2.

__global__ __launch_bounds__(256) void gat_aggregate_m4(const float* __restrict__ h,
                                                        const float* __restrict__ ssrc,
                                                        const float* __restrict__ sdst,
                                                        const int* __restrict__ offs,
                                                        const int* __restrict__ csr,
                                                        const float* __restrict__ bias,
                                                        float* __restrict__ out, int n) {
    int node = blockIdx.x * 4 + (threadIdx.x >> 6);
    int lane = threadIdx.x & 63;
    if (node >= n) return;
    const int hB = lane & 3;
    const int eL = lane >> 2;
    const int hA = lane >> 4;
    int beg = offs[node], end = offs[node + 1];
    float sd = sdst[node * 4 + hB];
    float m = -INFINITY, l = 0.f;
    float4 acc = make_float4(0.f, 0.f, 0.f, 0.f);

    for (int base = beg; base < end; base += 16) {
        int j = base + eL;
        bool valid = (j < end);
        int sj = valid ? csr[j] : 0;
        float logit = -INFINITY;
        if (valid) {
            float xv = ssrc[sj * 4 + hB] + sd;
            logit = (xv > 0.f) ? xv : NEG_SLOPE * xv;
        }
        float cm = logit;
        cm = fmaxf(cm, __shfl_xor(cm, 4));
        cm = fmaxf(cm, __shfl_xor(cm, 8));
        cm = fmaxf(cm, __shfl_xor(cm, 16));
        cm = fmaxf(cm, __shfl_xor(cm, 32));
        float nm = fmaxf(m, cm);
        float scale = __expf(m - nm);       // m=-inf -> 0
        float ex = valid ? __expf(logit - nm) : 0.f;
        float es = ex;
        es += __shfl_xor(es, 4);
        es += __shfl_xor(es, 8);
        es += __shfl_xor(es, 16);
        es += __shfl_xor(es, 32);
        l = l * scale + es;
        m = nm;
        float sA = __shfl(scale, hA);
        acc.x *= sA; acc.y *= sA; acc.z *= sA; acc.w *= sA;

        int cnt = min(16, end - base);
        for (int t = 0; t < cnt; t += 4) {
#pragma unroll
            for (int u = 0; u < 4; ++u) {
                int tt = t + u;
                float a = __shfl(ex, tt * 4 + hA);   // 0 for invalid edges
                int s = __shfl(sj, tt * 4);          // 0 for invalid (safe addr)
                const float4 hv = *(const float4*)&h[(size_t)s * 256 + lane * 4];
                acc.x = fmaf(a, hv.x, acc.x);
                acc.y = fmaf(a, hv.y, acc.y);
                acc.z = fmaf(a, hv.z, acc.z);
                acc.w = fmaf(a, hv.w, acc.w);
            }
        }
    }
    float lf = __shfl(l, hA);
    float inv = 1.f / lf;
    const float4 bv = *(const float4*)&bias[lane * 4];
    float4 o;
    o.x = fmaxf(fmaf(acc.x, inv, bv.x), 0.f);   // relu (layers 1 & 2)
    o.y = fmaxf(fmaf(acc.y, inv, bv.y), 0.f);
    o.z = fmaxf(fmaf(acc.z, inv, bv.z), 0.f);
    o.w = fmaxf(fmaf(acc.w, inv, bv.w), 0.f);
    *(float4*)&out[(size_t)node * 256 + lane * 4] = o;
}

// ---------------- Single-head aggregation (layer 3, C=32, no relu) --------

__global__ __launch_bounds__(256) void gat_aggregate_h1(const float* __restrict__ h,
                                                        const float* __restrict__ ssrc,
                                                        const float* __restrict__ sdst,
                                                        const int* __restrict__ offs,
                                                        const int* __restrict__ csr,
                                                        const float* __restrict__ bias,
                                                        float* __restrict__ out, int n) {
    int node = blockIdx.x * 4 + (threadIdx.x >> 6);
    int lane = threadIdx.x & 63;
    if (node >= n) return;
    int beg = offs[node], end = offs[node + 1];
    float sd = sdst[node];
    float m = -INFINITY, l = 0.f, acc = 0.f;

    for (int base = beg; base < end; base += 64) {
        int j = base + lane;
        bool valid = (j < end);
        int sj = valid ? csr[j] : 0;
        float logit = -INFINITY;
        if (valid) {
            float xv = ssrc[sj] + sd;
            logit = (xv > 0.f) ? xv : NEG_SLOPE * xv;
        }
        float cm = logit;
#pragma unroll
        for (int o = 32; o > 0; o >>= 1) cm = fmaxf(cm, __shfl_xor(cm, o));
        float nm = fmaxf(m, cm);
        float scale = __expf(m - nm);
        float ex = valid ? __expf(logit - nm) : 0.f;
        float es = ex;
#pragma unroll
        for (int o = 32; o > 0; o >>= 1) es += __shfl_xor(es, o);
        l = l * scale + es;
        m = nm;
        acc *= scale;
        int cnt = min(64, end - base);
        for (int t = 0; t < cnt; t += 4) {
#pragma unroll
            for (int u = 0; u < 4; ++u) {
                float a = __shfl(ex, t + u);
                int s = __shfl(sj, t + u);
                if (lane < 32) acc = fmaf(a, h[(size_t)s * 32 + lane], acc);
            }
        }
    }
    if (lane < 32) out[(size_t)node * 32 + lane] = acc / l + bias[lane];
}

// ---------------- Launch ----------------

extern "C" void kernel_launch(void* const* d_in, const int* in_sizes, int n_in,
                              void* d_out, int out_size, void* d_ws, size_t ws_size,
                              hipStream_t stream) {
    const float* x   = (const float*)d_in[0];
    const int*   ei  = (const int*)d_in[1];
    const float* W1  = (const float*)d_in[2];
    const float* as1 = (const float*)d_in[3];
    const float* ad1 = (const float*)d_in[4];
    const float* b1  = (const float*)d_in[5];
    const float* W2  = (const float*)d_in[6];
    const float* as2 = (const float*)d_in[7];
    const float* ad2 = (const float*)d_in[8];
    const float* b2  = (const float*)d_in[9];
    const float* W3  = (const float*)d_in[10];
    const float* as3 = (const float*)d_in[11];
    const float* ad3 = (const float*)d_in[12];
    const float* b3  = (const float*)d_in[13];
    float* out = (float*)d_out;

    const int n = in_sizes[0] / 3;     // 50000
    const int E = in_sizes[1] / 2;     // 400000
    const int Etot = E + n;            // with self-loops

    // workspace layout (fp32 activation ping-pong F1/F2)
    char* ws = (char*)d_ws;
    float* F1 = (float*)ws;  ws += (size_t)n * 256 * sizeof(float);   // 51.2 MB
    float* F2 = (float*)ws;  ws += (size_t)n * 256 * sizeof(float);   // 51.2 MB
    u16* Wt2h = (u16*)ws;    ws += (size_t)256 * 256 * sizeof(u16);
    u16* Wt2l = (u16*)ws;    ws += (size_t)256 * 256 * sizeof(u16);
    u16* Wt3h = (u16*)ws;    ws += (size_t)32 * 256 * sizeof(u16);
    u16* Wt3l = (u16*)ws;    ws += (size_t)32 * 256 * sizeof(u16);
    float* ssrc = (float*)ws;  ws += (size_t)n * 4 * sizeof(float);
    float* sdst = (float*)ws;  ws += (size_t)n * 4 * sizeof(float);
    int* deg    = (int*)ws;    ws += (size_t)n * sizeof(int);
    int* offs   = (int*)ws;    ws += (size_t)(n + 1) * sizeof(int) + 12;
    int* cursor = (int*)ws;    ws += (size_t)n * sizeof(int);
    int* csr    = (int*)ws;    ws += (size_t)Etot * sizeof(int);   // keep csr LAST

    // ---- CSR build (by dst) ----
    hipMemsetAsync(deg, 0, (size_t)n * sizeof(int), stream);
    int eblocks = (Etot + 255) / 256;
    edge_count<<<eblocks, 256, 0, stream>>>(ei, E, n, deg);
    scan_kernel<<<1, 1024, 0, stream>>>(deg, offs, cursor, n);
    edge_fill<<<eblocks, 256, 0, stream>>>(ei, E, n, cursor, csr);

    // ---- Weight prep (hi/lo split + transpose) ----
    transpose_split<<<(256 * 256 + 255) / 256, 256, 0, stream>>>(W2, Wt2h, Wt2l, 256, 256);
    transpose_split<<<(256 * 32 + 255) / 256, 256, 0, stream>>>(W3, Wt3h, Wt3l, 256, 32);

    int nb4 = (n + 3) / 4;
    int nb64 = (n + 63) / 64;

    // ---- Layer 1: 3 -> (4 x 64), concat, relu ----
    linear1<<<n, 256, 0, stream>>>(x, W1, F1, n);
    compute_scores<4, 64><<<n, 256, 0, stream>>>(F1, as1, ad1, ssrc, sdst, n);
    gat_aggregate_m4<<<nb4, 256, 0, stream>>>(F1, ssrc, sdst, offs, csr, b1, F2, n);

    // ---- Layer 2: 256 -> (4 x 64), concat, relu ----
    dim3 g2(nb64, 4);
    gemm_mfma_split<256><<<g2, 256, 0, stream>>>(F2, Wt2h, Wt2l, F1, n);
    compute_scores<4, 64><<<n, 256, 0, stream>>>(F1, as2, ad2, ssrc, sdst, n);
    gat_aggregate_m4<<<nb4, 256, 0, stream>>>(F1, ssrc, sdst, offs, csr, b2, F2, n);

    // ---- Layer 3: 256 -> (1 x 32), mean(=identity), no relu ----
    dim3 g3(nb64, 1);
    gemm_mfma_split<32><<<g3, 256, 0, stream>>>(F2, Wt3h, Wt3l, F1, n);
    compute_scores<1, 32><<<nb4, 256, 0, stream>>>(F1, as3, ad3, ssrc, sdst, n);
    gat_aggregate_h1<<<nb4, 256, 0, stream>>>(F1, ssrc, sdst, offs, csr, b3, out, n);
}